// Round 1
// baseline (105.676 us; speedup 1.0000x reference)
//
#include <hip/hip_runtime.h>

// BaseModel_3100966387783 — per-variable masked 3-layer MLP, b=8192, D=128, h=64, o=2.
//
// R4: identical to R3 (107.4 µs verified). Re-run after infra failure to
//     recapture baseline counters. Prediction: dur ~107 µs, MfmaUtil 10-15%,
//     OccupancyPercent ~25%, HBM <<10% peak -> latency-bound diagnosis.
//
// R3: brick layout (see R2) + register-resident weights + persistent bt-loop.
//   brick = 1 KB = 64 lanes x 16 B bf16; lane l holds T[tile*16 + (l&15)][ks*32 + (l>>4)*8 + 0..7]
//   = exactly one MFMA A/B fragment (load at base + lane*16, coalesced/conflict-free).
//
// brickify: fp32 -> bf16 bricks in d_ws (w0 pre-masked j==t -> 0, w2 zero-padded).
// fused_mlp: one block = (variable t, batch-group of 8 x 128-row tiles).
//   - all weight fragments global->VGPR once (104 regs), L2-resident
//   - loop 8 batch tiles: L0 -> wave-private LDS h bricks -> L1 -> (overwrite) -> L2
//   - x frags for iter s+1 prefetched into the same regs right after iter s's L0
//   - acc initialized with bias (C-operand trick); leaky = max(v, 0.01v)
//   - ZERO barriers, 16.4 KB LDS, 2 waves/SIMD by VGPR.

typedef __bf16 bf16_t;
typedef __bf16 bf16x8 __attribute__((ext_vector_type(8)));
typedef float  f32x4  __attribute__((ext_vector_type(4)));

#define LEAKY 0.01f

// ---------------- ws brick regions (byte offsets) ----------------
#define XB_OFF   0u                  // x bricks:   64 bt x 8 nt x 4 ks = 2048 bricks
#define W0B_OFF  (2048u*1024u)       // w0 masked: 128 t x 4 it x 4 ks = 2048
#define W1B_OFF  (4096u*1024u)       // w1:        128 t x 4 it x 2 ks = 1024
#define W2B_OFF  (5120u*1024u)       // w2 pad16:  128 t x 2 ks        =  256
// total ws need: 5376 KiB

// =================== pre-kernel: fp32 -> bf16 brick-ify ===================
__global__ __launch_bounds__(256)
void brickify(const float* __restrict__ x,  const float* __restrict__ w0,
              const float* __restrict__ w1, const float* __restrict__ w2,
              unsigned char* __restrict__ ws)
{
    const int wid  = blockIdx.x * 4 + (threadIdx.x >> 6);  // one wave = one brick
    const int lane = threadIdx.x & 63;
    const int lr = lane & 15, lq = lane >> 4;

    float v[8];
    if (wid < 2048) {                        // ---- x bricks ----
        int bt = wid >> 5, rem = wid & 31, nt = rem >> 2, ks = rem & 3;
        const float* s = x + (size_t)(bt*128 + nt*16 + lr) * 128 + ks*32 + lq*8;
        const float4 a = *(const float4*)s, b = *(const float4*)(s + 4);
        v[0]=a.x; v[1]=a.y; v[2]=a.z; v[3]=a.w;
        v[4]=b.x; v[5]=b.y; v[6]=b.z; v[7]=b.w;
    } else if (wid < 4096) {                 // ---- w0 bricks (masked) ----
        int u = wid - 2048, t = u >> 4, rem = u & 15, it = rem >> 2, ks = rem & 3;
        int k0 = ks*32 + lq*8;
        const float* s = w0 + (size_t)(t*64 + it*16 + lr) * 128 + k0;
        const float4 a = *(const float4*)s, b = *(const float4*)(s + 4);
        v[0]=a.x; v[1]=a.y; v[2]=a.z; v[3]=a.w;
        v[4]=b.x; v[5]=b.y; v[6]=b.z; v[7]=b.w;
        #pragma unroll
        for (int j = 0; j < 8; ++j) if (k0 + j == t) v[j] = 0.f;
    } else if (wid < 5120) {                 // ---- w1 bricks ----
        int u = wid - 4096, t = u >> 3, rem = u & 7, it = rem >> 1, ks = rem & 1;
        const float* s = w1 + (size_t)(t*64 + it*16 + lr) * 64 + ks*32 + lq*8;
        const float4 a = *(const float4*)s, b = *(const float4*)(s + 4);
        v[0]=a.x; v[1]=a.y; v[2]=a.z; v[3]=a.w;
        v[4]=b.x; v[5]=b.y; v[6]=b.z; v[7]=b.w;
    } else {                                 // ---- w2 bricks, rows>=2 zero ----
        int u = wid - 5120, t = u >> 1, ks = u & 1;
        #pragma unroll
        for (int j = 0; j < 8; ++j) v[j] = 0.f;
        if (lr < 2) {
            const float* s = w2 + (size_t)(t*2 + lr) * 64 + ks*32 + lq*8;
            const float4 a = *(const float4*)s, b = *(const float4*)(s + 4);
            v[0]=a.x; v[1]=a.y; v[2]=a.z; v[3]=a.w;
            v[4]=b.x; v[5]=b.y; v[6]=b.z; v[7]=b.w;
        }
    }
    union { bf16_t h[8]; uint4 q; } pk;
    #pragma unroll
    for (int j = 0; j < 8; ++j) pk.h[j] = (bf16_t)v[j];
    ((uint4*)ws)[(size_t)wid * 64 + lane] = pk.q;   // dst = brick*1024 + lane*16
}

// =========================== main fused kernel ===========================
__global__ __launch_bounds__(256, 2)
void fused_mlp(const unsigned char* __restrict__ ws,
               const float* __restrict__ b0, const float* __restrict__ b1,
               const float* __restrict__ b2, float* __restrict__ out)
{
    // h bricks only: 8 nt-tiles x 2 ks = 16 bricks, wave-private slices. No barriers.
    __shared__ __align__(16) unsigned char hsm[16384];

    const int tid  = threadIdx.x;
    const int w    = tid >> 6;         // wave 0..3: owns batch rows w*32 .. w*32+31
    const int lane = tid & 63;
    const int lr = lane & 15, lq = lane >> 4;
    const int g  = blockIdx.x;         // batch group: bt = g*8 + s
    const int t  = blockIdx.y;         // variable index

    // ---- weights: global -> registers (L2-hit, coalesced 1 KB/instr) ----
    const unsigned char* w0p = ws + W0B_OFF + (size_t)t*16384 + lane*16;
    const unsigned char* w1p = ws + W1B_OFF + (size_t)t*8192  + lane*16;
    const unsigned char* w2p = ws + W2B_OFF + (size_t)t*2048  + lane*16;
    bf16x8 w0f[4][4], w1f[4][2], w2f[2];
    #pragma unroll
    for (int it = 0; it < 4; ++it)
        #pragma unroll
        for (int ks = 0; ks < 4; ++ks)
            w0f[it][ks] = *(const bf16x8*)(w0p + (it*4+ks)*1024);
    #pragma unroll
    for (int it = 0; it < 4; ++it)
        #pragma unroll
        for (int ks = 0; ks < 2; ++ks)
            w1f[it][ks] = *(const bf16x8*)(w1p + (it*2+ks)*1024);
    #pragma unroll
    for (int ks = 0; ks < 2; ++ks)
        w2f[ks] = *(const bf16x8*)(w2p + ks*1024);

    // ---- biases: per-quad float4 (acc-init form) ----
    f32x4 b0q[4], b1q[4];
    #pragma unroll
    for (int it = 0; it < 4; ++it) {
        b0q[it] = *(const f32x4*)(b0 + t*64 + it*16 + lq*4);
        b1q[it] = *(const f32x4*)(b1 + t*64 + it*16 + lq*4);
    }
    const float2 b2v = *(const float2*)(b2 + t*2);

    // ---- x fragment pointer helper; preload iter 0 ----
    const unsigned char* xp = ws + XB_OFF + lane*16;
    bf16x8 xf[2][4];
    {
        const int bt0 = g*8;
        #pragma unroll
        for (int ntl = 0; ntl < 2; ++ntl)
            #pragma unroll
            for (int ks = 0; ks < 4; ++ks)
                xf[ntl][ks] = *(const bf16x8*)(xp + (size_t)(((bt0*8 + w*2+ntl)*4 + ks))*1024);
    }

    for (int s = 0; s < 8; ++s) {
        const int bt = g*8 + s;

        // ============ layer 0: D0[i][row] = w0m @ x^T (+b0 via C-init) ============
        f32x4 acc0[2][4];
        #pragma unroll
        for (int ntl = 0; ntl < 2; ++ntl)
            #pragma unroll
            for (int it = 0; it < 4; ++it) acc0[ntl][it] = b0q[it];

        #pragma unroll
        for (int ks = 0; ks < 4; ++ks)
            #pragma unroll
            for (int it = 0; it < 4; ++it)
                #pragma unroll
                for (int ntl = 0; ntl < 2; ++ntl)
                    acc0[ntl][it] = __builtin_amdgcn_mfma_f32_16x16x32_bf16(
                                        w0f[it][ks], xf[ntl][ks], acc0[ntl][it], 0, 0, 0);

        // ---- xf now dead: prefetch next iter's fragments into the same regs ----
        {
            const int btn = (s < 7) ? bt + 1 : bt;
            #pragma unroll
            for (int ntl = 0; ntl < 2; ++ntl)
                #pragma unroll
                for (int ks = 0; ks < 4; ++ks)
                    xf[ntl][ks] = *(const bf16x8*)(xp + (size_t)(((btn*8 + w*2+ntl)*4 + ks))*1024);
        }

        // epi0 -> h bricks: C reg r is k = it*16 + lq*4 + r (4 consecutive k) -> one b64
        #pragma unroll
        for (int ntl = 0; ntl < 2; ++ntl)
            #pragma unroll
            for (int it = 0; it < 4; ++it) {
                union { bf16_t h[4]; unsigned long long u; } pk;
                #pragma unroll
                for (int r = 0; r < 4; ++r) {
                    float u = acc0[ntl][it][r];
                    pk.h[r] = (bf16_t)fmaxf(u, LEAKY * u);
                }
                int off = ((w*2+ntl)*2 + (it>>1)) * 1024
                        + (((it&1)*2 + (lq>>1))*16 + lr) * 16 + (lq&1)*8;
                *(unsigned long long*)(hsm + off) = pk.u;
            }

        // ============ layer 1: D1[i2][row] = w1 @ h^T (+b1 via C-init) ============
        bf16x8 hf[2][2];
        #pragma unroll
        for (int ntl = 0; ntl < 2; ++ntl)
            #pragma unroll
            for (int ks = 0; ks < 2; ++ks)
                hf[ntl][ks] = *(const bf16x8*)(hsm + ((w*2+ntl)*2 + ks)*1024 + lane*16);

        f32x4 acc1[2][4];
        #pragma unroll
        for (int ntl = 0; ntl < 2; ++ntl)
            #pragma unroll
            for (int it = 0; it < 4; ++it) acc1[ntl][it] = b1q[it];

        #pragma unroll
        for (int ks = 0; ks < 2; ++ks)
            #pragma unroll
            for (int it = 0; it < 4; ++it)
                #pragma unroll
                for (int ntl = 0; ntl < 2; ++ntl)
                    acc1[ntl][it] = __builtin_amdgcn_mfma_f32_16x16x32_bf16(
                                        w1f[it][ks], hf[ntl][ks], acc1[ntl][it], 0, 0, 0);

        // epi1 -> h2 bricks, overwriting this wave's own h bricks (DS pipe is
        // in-order per wave; reads above already executed)
        #pragma unroll
        for (int ntl = 0; ntl < 2; ++ntl)
            #pragma unroll
            for (int it = 0; it < 4; ++it) {
                union { bf16_t h[4]; unsigned long long u; } pk;
                #pragma unroll
                for (int r = 0; r < 4; ++r) {
                    float u = acc1[ntl][it][r];
                    pk.h[r] = (bf16_t)fmaxf(u, LEAKY * u);
                }
                int off = ((w*2+ntl)*2 + (it>>1)) * 1024
                        + (((it&1)*2 + (lq>>1))*16 + lr) * 16 + (lq&1)*8;
                *(unsigned long long*)(hsm + off) = pk.u;
            }

        // ============ layer 2: D2[o][row] = w2pad @ h2^T ============
        bf16x8 h2f[2][2];
        #pragma unroll
        for (int ntl = 0; ntl < 2; ++ntl)
            #pragma unroll
            for (int ks = 0; ks < 2; ++ks)
                h2f[ntl][ks] = *(const bf16x8*)(hsm + ((w*2+ntl)*2 + ks)*1024 + lane*16);

        f32x4 acc2[2];
        acc2[0] = (f32x4){0.f,0.f,0.f,0.f};
        acc2[1] = (f32x4){0.f,0.f,0.f,0.f};
        #pragma unroll
        for (int ks = 0; ks < 2; ++ks)
            #pragma unroll
            for (int ntl = 0; ntl < 2; ++ntl)
                acc2[ntl] = __builtin_amdgcn_mfma_f32_16x16x32_bf16(
                                w2f[ks], h2f[ntl][ks], acc2[ntl], 0, 0, 0);

        // store: o=0,1 live in quad 0, regs 0,1 -> 8B per batch row
        if (lq == 0) {
            #pragma unroll
            for (int ntl = 0; ntl < 2; ++ntl) {
                int row = bt*128 + (w*2+ntl)*16 + lr;
                float2 o2 = { acc2[ntl][0] + b2v.x, acc2[ntl][1] + b2v.y };
                *(float2*)(out + (size_t)row*256 + t*2) = o2;
            }
        }
    }
}

extern "C" void kernel_launch(void* const* d_in, const int* in_sizes, int n_in,
                              void* d_out, int out_size, void* d_ws, size_t ws_size,
                              hipStream_t stream) {
    const float* x  = (const float*)d_in[0];
    const float* w0 = (const float*)d_in[1];
    const float* w1 = (const float*)d_in[2];
    const float* w2 = (const float*)d_in[3];
    const float* b0 = (const float*)d_in[4];
    const float* b1 = (const float*)d_in[5];
    const float* b2 = (const float*)d_in[6];
    unsigned char* ws = (unsigned char*)d_ws;   // needs 5376 KiB
    float* out = (float*)d_out;

    brickify<<<dim3(1344), dim3(256), 0, stream>>>(x, w0, w1, w2, ws);
    // grid (8 batch-groups, 128 t): 1024 blocks; if XCD = blockid%8, each XCD
    // sees one group's x bricks (256 KB) + all weights (3.3 MB) -> fits 4 MB L2.
    fused_mlp<<<dim3(8, 128), dim3(256), 0, stream>>>(ws, b0, b1, b2, out);
}